// Round 11
// baseline (258.054 us; speedup 1.0000x reference)
//
#include <hip/hip_runtime.h>
#include <hip/hip_bf16.h>
#include <math.h>

// Problem: MultiHeadSelfAttention  B=4, S=2048, D=1024, H=16, Hd=64
// fp32 in / fp32 out. bf16 scratch, fp32 accumulation.
// Round 20:
//  - gemm: A-direct-from-global (no LDS for A). Lane's A-frag for
//    mfma_16x16x32 is a contiguous 16B global load (row m0+wr*64+mi*16+l15,
//    cols t*32+quad*8); X is L3-resident, wc-pair dup hits L1/L2. A regs
//    double-buffered 1 K-step ahead. B keeps kgrp-major LDS (verified 0
//    conflicts), ring-3 x 8KB = 24KB. Per step: vmcnt(1) [outstanding =
//    {B(t),A(t)x4,B(t+1)}; releases B(t)+A(t)] -> barrier -> A(t+1)->regs
//    -> B(t+2)->LDS -> 16 MFMA. Issue order pinned with fences (vmcnt
//    counting depends on it). Rationale: R15-R19 mapped the LDS-staged
//    family (2ph geometries + 8ph port) = 93.6us floor; m233: its critical
//    path is the stage+vmcnt+barrier alignment -> remove A from it.
//  - attn: byte-identical to R15-verified.
// ws: Qb@0, Kb@16M, Vb@32M, Xb/Ob@48M (aliased). Wstash in d_out (dead
// until final GEMM); wo converted into Qb after attention frees it.

#define S_LEN 2048
#define DM    1024
#define NH    16
#define HD    64
#define M_ROWS 8192   // B * S

typedef __attribute__((ext_vector_type(8))) short bf16x8;
typedef __attribute__((ext_vector_type(4))) float f32x4;
typedef __attribute__((ext_vector_type(16))) float f32x16;

__device__ __forceinline__ float bf2f(unsigned short u) {
  union { unsigned int i; float f; } c; c.i = ((unsigned int)u) << 16; return c.f;
}
__device__ __forceinline__ unsigned short f2bf(float f) {
  unsigned int x = __float_as_uint(f);
  if ((x & 0x7fffffffu) > 0x7f800000u) return (unsigned short)0x7fc0u;  // NaN
  return (unsigned short)((x + 0x7fffu + ((x >> 16) & 1u)) >> 16);      // RNE
}
// async global->LDS, 16 B per lane; lds dest must be wave-uniform
__device__ __forceinline__ void gl_lds16(const unsigned short* g, unsigned short* l) {
  __builtin_amdgcn_global_load_lds(
      (const __attribute__((address_space(1))) unsigned int*)g,
      (__attribute__((address_space(3))) unsigned int*)l, 16, 0, 0);
}

#define FENCE() asm volatile("" ::: "memory")

// ---------------------------------------------------------------------------
// fp32 -> bf16 bulk convert (8 elems/thread)
// ---------------------------------------------------------------------------
__global__ __launch_bounds__(256) void cvt_bf16(const float* __restrict__ in,
                                                unsigned short* __restrict__ out) {
  const int i = blockIdx.x * 256 + threadIdx.x;
  float4 a = ((const float4*)in)[2 * i];
  float4 b = ((const float4*)in)[2 * i + 1];
  ushort4 r0, r1;
  r0.x = f2bf(a.x); r0.y = f2bf(a.y); r0.z = f2bf(a.z); r0.w = f2bf(a.w);
  r1.x = f2bf(b.x); r1.y = f2bf(b.y); r1.z = f2bf(b.z); r1.w = f2bf(b.w);
  ((ushort4*)out)[2 * i] = r0;
  ((ushort4*)out)[2 * i + 1] = r1;
}

// convert wq,wk,wv (1M fp32 each) into one contiguous bf16 stash [3072][1024]
__global__ __launch_bounds__(256) void cvt_w3(const float* __restrict__ w0,
                                              const float* __restrict__ w1,
                                              const float* __restrict__ w2,
                                              unsigned short* __restrict__ out) {
  const int idx = blockIdx.x;                 // 0..1535
  const int which = idx >> 9;
  const float* src = (which == 0) ? w0 : (which == 1) ? w1 : w2;
  unsigned short* dst = out + (size_t)which * (DM * DM);
  const int i = (idx & 511) * 256 + threadIdx.x;
  float4 a = ((const float4*)src)[2 * i];
  float4 b = ((const float4*)src)[2 * i + 1];
  ushort4 r0, r1;
  r0.x = f2bf(a.x); r0.y = f2bf(a.y); r0.z = f2bf(a.z); r0.w = f2bf(a.w);
  r1.x = f2bf(b.x); r1.y = f2bf(b.y); r1.z = f2bf(b.z); r1.w = f2bf(b.w);
  ((ushort4*)dst)[2 * i] = r0;
  ((ushort4*)dst)[2 * i + 1] = r1;
}

// ---------------------------------------------------------------------------
// MFMA GEMM: A direct-from-global to registers, B via LDS ring-3.
// C[m,e] = sum_d A[m,d] * Wall[e,d].  BM=256 x BN=128, BK=32, 8 waves,
// wave (wr=w>>1, wc=w&1) owns 64x64, acc[4][4].
// Bs per buffer: [4 kgrp][128 rows][8] = 8KB; ring-3 = 24KB.
// B staging: wave w stages kgrp=w>>1, rows (w&1)*64+lane (1 gl_lds16/tile).
// A frags: af[mi] = X[(m0+wr*64+mi*16+l15)*DM + t*32 + quad*8] (16B/lane),
// double-buffered regs (aA/aB), loaded 1 K-step ahead.
// Steady iter t: vmcnt(1) [out = {B(t),A(t)x4,B(t+1)} -> releases B(t),A(t)]
// -> barrier -> LDA(t+1) -> STB(t+2) -> 16 MFMA. Fences pin issue order.
// Tail: iter30 (no STB), iter31 vmcnt(0).
// OUT_MODE 0: bf16*(z?1:0.125) scatter to [z][B,H,S,Hd], z=e>>10.
// OUT_MODE 1: fp32 row-major to outF.
// ---------------------------------------------------------------------------
template <int OUT_MODE>
__global__ __launch_bounds__(512, 4) void gemm_bt(const unsigned short* __restrict__ A,
                                                  const unsigned short* __restrict__ Wall,
                                                  unsigned short* __restrict__ outB,
                                                  float* __restrict__ outF) {
  __shared__ __align__(16) unsigned short Bs[3 * 4096];  // [buf][kgrp4][128][8]
  const int m0 = blockIdx.x * 256;
  const int n0 = blockIdx.y * 128;
  const int tid = threadIdx.x;
  const int lane = tid & 63, w = tid >> 6;   // 8 waves
  const int quad = lane >> 4, l15 = lane & 15;
  const int wr = w >> 1, wc = w & 1;         // compute mapping: 4M x 2N waves

  // A fragment base: row (m0 + wr*64 + l15), col quad*8; frag mi adds 16*DM
  const unsigned short* agA = A + (size_t)(m0 + wr * 64 + l15) * DM + quad * 8;
  // B staging map: wave w -> kgrp w>>1, row-half w&1
  const unsigned short* bgB = Wall + (size_t)(n0 + (w & 1) * 64 + lane) * DM + (w >> 1) * 8;
  const int sB  = (w >> 1) * 1024 + (w & 1) * 512;     // wave-uniform elem base
  const int raB = quad * 1024 + (wc * 64 + l15) * 8;   // B frag-read base

  f32x4 acc[4][4];
#pragma unroll
  for (int i = 0; i < 4; ++i)
#pragma unroll
    for (int j = 0; j < 4; ++j) { acc[i][j].x = 0.f; acc[i][j].y = 0.f; acc[i][j].z = 0.f; acc[i][j].w = 0.f; }

  bf16x8 aA[4], aB[4];

#define LDA_INTO(DST_, T_) do {                                              \
    DST_[0] = *(const bf16x8*)(agA + (size_t)(T_) * 32);                     \
    DST_[1] = *(const bf16x8*)(agA + (size_t)(T_) * 32 + 16 * DM);           \
    DST_[2] = *(const bf16x8*)(agA + (size_t)(T_) * 32 + 32 * DM);           \
    DST_[3] = *(const bf16x8*)(agA + (size_t)(T_) * 32 + 48 * DM);           \
  } while (0)

#define STB(T_, S_) gl_lds16(bgB + (size_t)(T_) * 32, &Bs[(S_) * 4096 + sB])

#define CMP(SRC_, CB_) do {                                                  \
    bf16x8 bq_[4];                                                           \
    _Pragma("unroll")                                                        \
    for (int ni = 0; ni < 4; ++ni)                                           \
      bq_[ni] = *(const bf16x8*)&Bs[(CB_) * 4096 + raB + ni * 128];          \
    __builtin_amdgcn_s_setprio(1);                                           \
    _Pragma("unroll")                                                        \
    for (int mi = 0; mi < 4; ++mi)                                           \
      _Pragma("unroll")                                                      \
      for (int ni = 0; ni < 4; ++ni)                                         \
        acc[mi][ni] = __builtin_amdgcn_mfma_f32_16x16x32_bf16(SRC_[mi], bq_[ni], acc[mi][ni], 0, 0, 0); \
    __builtin_amdgcn_s_setprio(0);                                           \
  } while (0)

#define VM1 asm volatile("s_waitcnt vmcnt(1)" ::: "memory")
#define VM0 asm volatile("s_waitcnt vmcnt(0)" ::: "memory")

// steady iteration: compute tile T_ from regs CUR_ + LDS buf CB_;
// prefetch A(T_+1) into NXT_, stage B(T_+2) into buf SB_
#define ITER(T_, CUR_, NXT_, CB_, SB_) do {                                  \
    VM1;                                                                     \
    __builtin_amdgcn_s_barrier();                                            \
    FENCE();                                                                 \
    LDA_INTO(NXT_, (T_) + 1);                                                \
    FENCE();                                                                 \
    STB((T_) + 2, SB_);                                                      \
    FENCE();                                                                 \
    CMP(CUR_, CB_);                                                          \
    FENCE();                                                                 \
  } while (0)

  // prologue (issue order matters for vmcnt counting): B(0), A(0)x4, B(1)
  STB(0, 0);
  FENCE();
  LDA_INTO(aA, 0);
  FENCE();
  STB(1, 1);
  FENCE();

  // main: iterations 0..29 (unroll 6: lcm of buf period 3, reg parity 2)
  for (int t = 0; t < 30; t += 6) {
    ITER(t,     aA, aB, 0, 2);
    ITER(t + 1, aB, aA, 1, 0);
    ITER(t + 2, aA, aB, 2, 1);
    ITER(t + 3, aB, aA, 0, 2);
    ITER(t + 4, aA, aB, 1, 0);
    ITER(t + 5, aB, aA, 2, 1);
  }
  // iter 30: outstanding {B(30),A(30)x4,B(31)} -> vmcnt(1); no B-stage
  VM1;
  __builtin_amdgcn_s_barrier();
  FENCE();
  LDA_INTO(aB, 31);
  FENCE();
  CMP(aA, 0);
  FENCE();
  // iter 31: outstanding {B(31),A(31)x4} -> vmcnt(0)
  VM0;
  __builtin_amdgcn_s_barrier();
  FENCE();
  CMP(aB, 1);

#undef ITER
#undef VM0
#undef VM1
#undef CMP
#undef STB
#undef LDA_INTO

  const float oscale = (OUT_MODE == 0 && n0 < 1024) ? 0.125f : 1.0f;
#pragma unroll
  for (int mi = 0; mi < 4; ++mi) {
#pragma unroll
    for (int reg = 0; reg < 4; ++reg) {
      const int m = m0 + wr * 64 + mi * 16 + quad * 4 + reg;
#pragma unroll
      for (int ni = 0; ni < 4; ++ni) {
        const int e = n0 + wc * 64 + ni * 16 + l15;
        const float v = acc[mi][ni][reg];
        if (OUT_MODE == 0) {
          const int z = e >> 10;                   // 0:Q 1:K 2:V
          const int e10 = e & 1023;
          const int b = m >> 11, s = m & (S_LEN - 1);
          const int h = e10 >> 6, hd = e10 & 63;
          outB[(size_t)z * (M_ROWS * DM) +
               (((size_t)(b * NH + h)) * S_LEN + s) * HD + hd] = f2bf(v * oscale);
        } else {
          outF[(size_t)m * DM + e] = v;
        }
      }
    }
  }
}

// ---------------------------------------------------------------------------
// MFMA flash attention on 32x32x16, swapped QK^T, in-register softmax+P.
// (R15-verified; see that round's header comment for the layout derivation.)
// ---------------------------------------------------------------------------
__global__ __launch_bounds__(256, 4) void attn_mfma(const unsigned short* __restrict__ Q,
                                                    const unsigned short* __restrict__ K,
                                                    const unsigned short* __restrict__ V,
                                                    unsigned short* __restrict__ O) {
  __shared__ unsigned short Ks[64][72];
  __shared__ unsigned short Vt[64][72];
  const int bh = blockIdx.x;                 // 0..63
  const int bx = 15 - (int)blockIdx.y;       // heavy q-blocks dispatched first
  const int tid = threadIdx.x;
  const int w = tid >> 6, lane = tid & 63;
  const int l31 = lane & 31, hi = lane >> 5;
  const size_t base = (size_t)bh * S_LEN * HD;
  const int b = bh >> 4, h = bh & 15;
  const int wq0 = bx * 128 + w * 32;
  const int diag_jt = 2 * bx + (w >> 1);     // wave's last (and partial) tile
  const int jt_blk = 2 * bx + 1;             // block's last tile
  const int kr0 = tid >> 3, kc0 = (tid & 7) * 8;
  const int vs = (tid & 31) * 2, vh = (tid >> 5) * 8;

  // Q fragments (B-operand): lane (hi,q=l31) holds d = ds*16 + hi*8 + e
  bf16x8 qb[4];
#pragma unroll
  for (int ds = 0; ds < 4; ++ds)
    qb[ds] = *(const bf16x8*)(Q + base + (size_t)(wq0 + l31) * HD + ds * 16 + hi * 8);

  f32x16 o0, o1;
#pragma unroll
  for (int r = 0; r < 16; ++r) { o0[r] = 0.f; o1[r] = 0.f; }
  float l_acc = 0.f;

  for (int jt = 0; jt <= jt_blk; ++jt) {
    __syncthreads();
    {
      const unsigned short* kgp = K + base + (size_t)jt * 64 * HD;
      const unsigned short* vgp = V + base + (size_t)jt * 64 * HD;
      *(uint4*)&Ks[kr0][kc0]      = *(const uint4*)(kgp + kr0 * HD + kc0);
      *(uint4*)&Ks[kr0 + 32][kc0] = *(const uint4*)(kgp + (kr0 + 32) * HD + kc0);
      uint4 r0 = *(const uint4*)(vgp + (size_t)vs * HD + vh);
      uint4 r1 = *(const uint4*)(vgp + (size_t)(vs + 1) * HD + vh);
      const unsigned int* a0 = (const unsigned int*)&r0;
      const unsigned int* a1 = (const unsigned int*)&r1;
#pragma unroll
      for (int j = 0; j < 4; ++j) {
        *(unsigned int*)&Vt[vh + 2 * j][vs]     = __builtin_amdgcn_perm(a1[j], a0[j], 0x05040100u);
        *(unsigned int*)&Vt[vh + 2 * j + 1][vs] = __builtin_amdgcn_perm(a1[j], a0[j], 0x07060302u);
      }
    }
    __syncthreads();

    if (jt <= diag_jt) {                      // wave-uniform
      const bool diag = (jt == diag_jt);
      for (int kb = 0; kb < 2; ++kb) {
        const bool kb_zero = diag && ((w & 1) == 0) && (kb == 1);
        const bool kb_part = diag && (kb == (w & 1));
        if (kb_zero) continue;                // wave-uniform; no contribution

        f32x16 sa;
#pragma unroll
        for (int r = 0; r < 16; ++r) sa[r] = 0.f;
        __builtin_amdgcn_s_setprio(1);
#pragma unroll
        for (int ds = 0; ds < 4; ++ds) {
          bf16x8 kf = *(const bf16x8*)&Ks[kb * 32 + l31][ds * 16 + hi * 8];
          sa = __builtin_amdgcn_mfma_f32_32x32x16_bf16(kf, qb[ds], sa, 0, 0, 0);
        }
        __builtin_amdgcn_s_setprio(0);

        float p[16];
        if (kb_part) {
#pragma unroll
          for (int r = 0; r < 16; ++r) {
            const int krel = (r & 3) + 8 * (r >> 2) + 4 * hi;
            p[r] = __expf((l31 >= krel) ? sa[r] : -1.0e30f);
          }
        } else {
#pragma unroll
          for (int r = 0; r < 16; ++r) p[r] = __expf(sa[r]);
        }
        l_acc += (((p[0] + p[1]) + (p[2] + p[3])) + ((p[4] + p[5]) + (p[6] + p[7])))
               + (((p[8] + p[9]) + (p[10] + p[11])) + ((p[12] + p[13]) + (p[14] + p[15])));

        unsigned int pk[8], sk[8];
#pragma unroll
        for (int g = 0; g < 4; ++g) {
          pk[2 * g]     = __builtin_amdgcn_perm(__float_as_uint(p[4 * g + 1]), __float_as_uint(p[4 * g]),     0x07060302u);
          pk[2 * g + 1] = __builtin_amdgcn_perm(__float_as_uint(p[4 * g + 3]), __float_as_uint(p[4 * g + 2]), 0x07060302u);
        }
#pragma unroll
        for (int i = 0; i < 8; ++i) sk[i] = (unsigned int)__shfl_xor((int)pk[i], 32);

#pragma unroll
        for (int sl = 0; sl < 2; ++sl) {
          const int g0 = 2 * sl, g1 = 2 * sl + 1;
          union { unsigned int u[4]; bf16x8 v; } fa;
          fa.u[0] = hi ? sk[2 * g1]     : pk[2 * g0];
          fa.u[1] = hi ? sk[2 * g1 + 1] : pk[2 * g0 + 1];
          fa.u[2] = hi ? pk[2 * g1]     : sk[2 * g0];
          fa.u[3] = hi ? pk[2 * g1 + 1] : sk[2 * g0 + 1];
          const int s = kb * 2 + sl;
          bf16x8 v0 = *(const bf16x8*)&Vt[l31][s * 16 + hi * 8];
          bf16x8 v1 = *(const bf16x8*)&Vt[32 + l31][s * 16 + hi * 8];
          __builtin_amdgcn_s_setprio(1);
          o0 = __builtin_amdgcn_mfma_f32_32x32x16_bf16(fa.v, v0, o0, 0, 0, 0);
          o1 = __builtin_amdgcn_mfma_f32_32x32x16_bf16(fa.v, v1, o1, 0, 0, 0);
          __builtin_amdgcn_s_setprio(0);
        }
      }
    }
  }

  // epilogue: l total (xor32 joins the two k-halves), scale + write O
  const float lf = l_acc + __shfl_xor(l_acc, 32);
  const float inv = 1.0f / lf;
#pragma unroll
  for (int r = 0; r < 16; ++r) {
    const int qrel = (r & 3) + 8 * (r >> 2) + 4 * hi;
    const float invr = __shfl(inv, qrel);    // lane qrel holds l for q=wq0+qrel
    const size_t orow = (size_t)(b * S_LEN + wq0 + qrel) * DM + h * HD;
    O[orow + l31]      = f2bf(o0[r] * invr);
    O[orow + 32 + l31] = f2bf(o1[r] * invr);
  }
}

extern "C" void kernel_launch(void* const* d_in, const int* in_sizes, int n_in,
                              void* d_out, int out_size, void* d_ws, size_t ws_size,
                              hipStream_t stream) {
  const float* x  = (const float*)d_in[0];  // fp32 [4,2048,1024]
  const float* wq = (const float*)d_in[1];  // fp32 [1024,1024]
  const float* wk = (const float*)d_in[2];
  const float* wv = (const float*)d_in[3];
  const float* wo = (const float*)d_in[4];

  unsigned short* Qb = (unsigned short*)d_ws;                 // 16 MB
  unsigned short* Kb = Qb + (size_t)M_ROWS * DM;              // 16 MB (Qb+z*16M)
  unsigned short* Vb = Kb + (size_t)M_ROWS * DM;              // 16 MB
  unsigned short* Xb = Vb + (size_t)M_ROWS * DM;              // 16 MB (alias Ob)
  unsigned short* Ob = Xb;
  (void)Kb; (void)Vb;

  // bf16 weight stash inside d_out (32 MB fp32 buffer; dead until final GEMM)
  unsigned short* Wstash = (unsigned short*)d_out;            // [3072][1024] bf16

  dim3 bb(256);
  dim3 gb(512);

  hipLaunchKernelGGL(cvt_bf16, dim3((M_ROWS * DM) / 2048), bb, 0, stream, x, Xb);
  hipLaunchKernelGGL(cvt_w3, dim3(3 * (DM * DM) / 2048), bb, 0, stream, wq, wk, wv, Wstash);
  // fused QKV as single GEMM: M=8192, N=3072 (z = e>>10 selects output slab)
  hipLaunchKernelGGL((gemm_bt<0>), dim3(M_ROWS / 256, 3 * DM / 128), gb, 0, stream,
                     Xb, Wstash, Qb, (float*)nullptr);
  hipLaunchKernelGGL(attn_mfma, dim3(64, 16), bb, 0, stream, Qb, Qb + (size_t)M_ROWS * DM,
                     Qb + 2 * (size_t)M_ROWS * DM, Ob);
  // wo -> bf16 into Qb (free after attention); then final projection
  hipLaunchKernelGGL(cvt_bf16, dim3((DM * DM) / 2048), bb, 0, stream, wo, Qb);
  hipLaunchKernelGGL((gemm_bt<1>), dim3(M_ROWS / 256, DM / 128), gb, 0, stream,
                     Ob, Qb, (unsigned short*)nullptr, (float*)d_out);
}

// Round 12
// 199.262 us; speedup vs baseline: 1.2951x; 1.2951x over previous
//
#include <hip/hip_runtime.h>
#include <hip/hip_bf16.h>
#include <math.h>

// Problem: MultiHeadSelfAttention  B=4, S=2048, D=1024, H=16, Hd=64
// fp32 in / fp32 out. bf16 scratch, fp32 accumulation.
// Round 21 (recombination of verified-best components):
//  - QKV gemm: R16 exact (ring-3 counted-vmcnt, 256x128, 8 waves, 1 barrier
//    per K-step; 93.6us verified twice). Structure ledger R11..R20: every
//    deviation (4w, 128^2-for-QKV, 8-phase port, A-direct) regressed.
//  - final gemm: R18-verified 128^2/4w structure (512 blocks = 2-3/CU
//    overlapping pipelines vs 256 blocks = 1/CU for 256x128). Ledger
//    subtraction: R18 non-QKV residual 103.1us vs R16 106.4 -> ~3us win.
//  - attn: R15-verified 32x32 swapped-QK in-register softmax, frozen.
// ws: Qb@0, Kb@16M, Vb@32M, Xb/Ob@48M (aliased). Wstash in d_out (dead
// until final GEMM); wo converted into Qb after attention frees it.

#define S_LEN 2048
#define DM    1024
#define NH    16
#define HD    64
#define M_ROWS 8192   // B * S

typedef __attribute__((ext_vector_type(8))) short bf16x8;
typedef __attribute__((ext_vector_type(4))) float f32x4;
typedef __attribute__((ext_vector_type(16))) float f32x16;

__device__ __forceinline__ float bf2f(unsigned short u) {
  union { unsigned int i; float f; } c; c.i = ((unsigned int)u) << 16; return c.f;
}
__device__ __forceinline__ unsigned short f2bf(float f) {
  unsigned int x = __float_as_uint(f);
  if ((x & 0x7fffffffu) > 0x7f800000u) return (unsigned short)0x7fc0u;  // NaN
  return (unsigned short)((x + 0x7fffu + ((x >> 16) & 1u)) >> 16);      // RNE
}
// async global->LDS, 16 B per lane; lds dest must be wave-uniform
__device__ __forceinline__ void gl_lds16(const unsigned short* g, unsigned short* l) {
  __builtin_amdgcn_global_load_lds(
      (const __attribute__((address_space(1))) unsigned int*)g,
      (__attribute__((address_space(3))) unsigned int*)l, 16, 0, 0);
}

#define FENCE() asm volatile("" ::: "memory")

// ---------------------------------------------------------------------------
// fp32 -> bf16 bulk convert (8 elems/thread)
// ---------------------------------------------------------------------------
__global__ __launch_bounds__(256) void cvt_bf16(const float* __restrict__ in,
                                                unsigned short* __restrict__ out) {
  const int i = blockIdx.x * 256 + threadIdx.x;
  float4 a = ((const float4*)in)[2 * i];
  float4 b = ((const float4*)in)[2 * i + 1];
  ushort4 r0, r1;
  r0.x = f2bf(a.x); r0.y = f2bf(a.y); r0.z = f2bf(a.z); r0.w = f2bf(a.w);
  r1.x = f2bf(b.x); r1.y = f2bf(b.y); r1.z = f2bf(b.z); r1.w = f2bf(b.w);
  ((ushort4*)out)[2 * i] = r0;
  ((ushort4*)out)[2 * i + 1] = r1;
}

// convert wq,wk,wv (1M fp32 each) into one contiguous bf16 stash [3072][1024]
__global__ __launch_bounds__(256) void cvt_w3(const float* __restrict__ w0,
                                              const float* __restrict__ w1,
                                              const float* __restrict__ w2,
                                              unsigned short* __restrict__ out) {
  const int idx = blockIdx.x;                 // 0..1535
  const int which = idx >> 9;
  const float* src = (which == 0) ? w0 : (which == 1) ? w1 : w2;
  unsigned short* dst = out + (size_t)which * (DM * DM);
  const int i = (idx & 511) * 256 + threadIdx.x;
  float4 a = ((const float4*)src)[2 * i];
  float4 b = ((const float4*)src)[2 * i + 1];
  ushort4 r0, r1;
  r0.x = f2bf(a.x); r0.y = f2bf(a.y); r0.z = f2bf(a.z); r0.w = f2bf(a.w);
  r1.x = f2bf(b.x); r1.y = f2bf(b.y); r1.z = f2bf(b.z); r1.w = f2bf(b.w);
  ((ushort4*)dst)[2 * i] = r0;
  ((ushort4*)dst)[2 * i + 1] = r1;
}

// ---------------------------------------------------------------------------
// QKV GEMM (R16 exact): counted-vmcnt ring-3, 256x128, 8 waves, 1 bar/K-step.
// C[m,e] = sum_d A[m,d] * Wall[e,d].  bf16 out, z-slab scatter.
// Per K-step: vmcnt(3) [outstanding = tiles t,t+1 = 6; release t] ->
// s_barrier -> STAGE3(t+2) -> COMPUTE(t).
// ---------------------------------------------------------------------------
__global__ __launch_bounds__(512, 4) void gemm_qkv(const unsigned short* __restrict__ A,
                                                   const unsigned short* __restrict__ Wall,
                                                   unsigned short* __restrict__ outB) {
  __shared__ __align__(16) unsigned short As[3 * 8192];  // [buf][kgrp4][256][8]
  __shared__ __align__(16) unsigned short Bs[3 * 4096];  // [buf][kgrp4][128][8]
  const int m0 = blockIdx.x * 256;
  const int n0 = blockIdx.y * 128;
  const int tid = threadIdx.x;
  const int lane = tid & 63, w = tid >> 6;
  const int quad = lane >> 4, l15 = lane & 15;
  const int wrow = w >> 1, wcol = w & 1;    // compute mapping: 4M x 2N waves

  // staging map (independent of compute mapping)
  const int mh  = 0;
  (void)mh;
  const int skg = w & 3, srq = w >> 2;
  const unsigned short* agA = A    + (size_t)(m0 + srq * 64 + lane) * DM + skg * 8;
  const unsigned short* bgB = Wall + (size_t)(n0 + srq * 64 + lane) * DM + skg * 8;
  const int lA0 = skg * 2048 + srq * 512;   // wave-uniform LDS elem offsets
  const int lA1 = lA0 + 1024;               // rows +128
  const int lB  = skg * 1024 + srq * 512;
  const int raA = quad * 2048 + (wrow * 64 + l15) * 8;  // frag-read bases
  const int raB = quad * 1024 + (wcol * 64 + l15) * 8;

  f32x4 acc[4][4];
#pragma unroll
  for (int i = 0; i < 4; ++i)
#pragma unroll
    for (int j = 0; j < 4; ++j) { acc[i][j].x = 0.f; acc[i][j].y = 0.f; acc[i][j].z = 0.f; acc[i][j].w = 0.f; }

#define STAGE3(T, SB) do {                                                   \
    const unsigned short* ap_ = agA + (size_t)(T) * 32;                      \
    gl_lds16(ap_,          &As[(SB) * 8192 + lA0]);                          \
    gl_lds16(ap_ + 131072, &As[(SB) * 8192 + lA1]);                          \
    gl_lds16(bgB + (size_t)(T) * 32, &Bs[(SB) * 4096 + lB]);                 \
  } while (0)

#define COMPUTE(CB) do {                                                     \
    bf16x8 af_[4], bq_[4];                                                   \
    _Pragma("unroll")                                                        \
    for (int mi = 0; mi < 4; ++mi)                                           \
      af_[mi] = *(const bf16x8*)&As[(CB) * 8192 + raA + mi * 128];           \
    _Pragma("unroll")                                                        \
    for (int ni = 0; ni < 4; ++ni)                                           \
      bq_[ni] = *(const bf16x8*)&Bs[(CB) * 4096 + raB + ni * 128];           \
    __builtin_amdgcn_s_setprio(1);                                           \
    _Pragma("unroll")                                                        \
    for (int mi = 0; mi < 4; ++mi)                                           \
      _Pragma("unroll")                                                      \
      for (int ni = 0; ni < 4; ++ni)                                         \
        acc[mi][ni] = __builtin_amdgcn_mfma_f32_16x16x32_bf16(af_[mi], bq_[ni], acc[mi][ni], 0, 0, 0); \
    __builtin_amdgcn_s_setprio(0);                                           \
  } while (0)

#define SUBSTEP(T, SB, CB) do {                                              \
    asm volatile("s_waitcnt vmcnt(3)" ::: "memory");                         \
    __builtin_amdgcn_s_barrier();                                            \
    FENCE();                                                                 \
    STAGE3((T), (SB));                                                       \
    COMPUTE(CB);                                                             \
    FENCE();                                                                 \
  } while (0)

  // prologue: tiles 0,1 into bufs 0,1 (ring fills; no wait yet)
  STAGE3(0, 0);
  STAGE3(1, 1);

  // main loop: 30 tiles, unrolled x3 for compile-time buffer indices
  for (int t = 0; t < 30; t += 3) {
    SUBSTEP(t + 2, 2, 0);
    SUBSTEP(t + 3, 0, 1);
    SUBSTEP(t + 4, 1, 2);
  }
  // drain: tile 30 in buf0 (tile 31 still in flight), then tile 31 in buf1
  asm volatile("s_waitcnt vmcnt(3)" ::: "memory");
  __builtin_amdgcn_s_barrier();
  FENCE();
  COMPUTE(0);
  asm volatile("s_waitcnt vmcnt(0)" ::: "memory");
  __builtin_amdgcn_s_barrier();
  FENCE();
  COMPUTE(1);

#undef SUBSTEP
#undef COMPUTE
#undef STAGE3

  const float oscale = (n0 < 1024) ? 0.125f : 1.0f;
#pragma unroll
  for (int mi = 0; mi < 4; ++mi) {
#pragma unroll
    for (int reg = 0; reg < 4; ++reg) {
      const int m = m0 + wrow * 64 + mi * 16 + quad * 4 + reg;
#pragma unroll
      for (int ni = 0; ni < 4; ++ni) {
        const int e = n0 + wcol * 64 + ni * 16 + l15;
        const float v = acc[mi][ni][reg];
        const int z = e >> 10;                   // 0:Q 1:K 2:V
        const int e10 = e & 1023;
        const int b = m >> 11, s = m & (S_LEN - 1);
        const int h = e10 >> 6, hd = e10 & 63;
        outB[(size_t)z * (M_ROWS * DM) +
             (((size_t)(b * NH + h)) * S_LEN + s) * HD + hd] = f2bf(v * oscale);
      }
    }
  }
}

// ---------------------------------------------------------------------------
// Final GEMM (R18-verified 128^2/4w structure): counted-vmcnt ring-3,
// 128x128 tile, 4 waves, 48KB LDS -> 2-3 blocks/CU; grid 64x8 = 512 blocks.
// fp32 row-major output.
// ---------------------------------------------------------------------------
__global__ __launch_bounds__(256, 2) void gemm_out(const unsigned short* __restrict__ A,
                                                   const unsigned short* __restrict__ Wb,
                                                   float* __restrict__ outF) {
  __shared__ __align__(16) unsigned short As[3 * 4096];  // [buf][kgrp4][128][8]
  __shared__ __align__(16) unsigned short Bs[3 * 4096];
  const int m0 = blockIdx.x * 128;
  const int n0 = blockIdx.y * 128;
  const int tid = threadIdx.x;
  const int lane = tid & 63, w = tid >> 6;   // 4 waves
  const int quad = lane >> 4, l15 = lane & 15;
  const int wr = w >> 1, wc = w & 1;         // compute mapping: 2M x 2N waves

  // staging map: wave w owns kgrp = w
  const unsigned short* agA = A  + (size_t)(m0 + lane) * DM + w * 8;
  const unsigned short* bgB = Wb + (size_t)(n0 + lane) * DM + w * 8;
  const int lA0 = w * 1024;                  // elem base (kgrp=w, rows 0..63)
  const int lB0 = w * 1024;
  const int raA = quad * 1024 + (wr * 64 + l15) * 8;  // frag-read bases
  const int raB = quad * 1024 + (wc * 64 + l15) * 8;

  f32x4 acc[4][4];
#pragma unroll
  for (int i = 0; i < 4; ++i)
#pragma unroll
    for (int j = 0; j < 4; ++j) { acc[i][j].x = 0.f; acc[i][j].y = 0.f; acc[i][j].z = 0.f; acc[i][j].w = 0.f; }

#define STAGE4(T, SB) do {                                                   \
    const unsigned short* ap_ = agA + (size_t)(T) * 32;                      \
    const unsigned short* bp_ = bgB + (size_t)(T) * 32;                      \
    gl_lds16(ap_,           &As[(SB) * 4096 + lA0]);                         \
    gl_lds16(ap_ + 64 * DM, &As[(SB) * 4096 + lA0 + 512]);                   \
    gl_lds16(bp_,           &Bs[(SB) * 4096 + lB0]);                         \
    gl_lds16(bp_ + 64 * DM, &Bs[(SB) * 4096 + lB0 + 512]);                   \
  } while (0)

#define COMPUTE(CB) do {                                                     \
    bf16x8 af_[4], bq_[4];                                                   \
    _Pragma("unroll")                                                        \
    for (int mi = 0; mi < 4; ++mi)                                           \
      af_[mi] = *(const bf16x8*)&As[(CB) * 4096 + raA + mi * 128];           \
    _Pragma("unroll")                                                        \
    for (int ni = 0; ni < 4; ++ni)                                           \
      bq_[ni] = *(const bf16x8*)&Bs[(CB) * 4096 + raB + ni * 128];           \
    __builtin_amdgcn_s_setprio(1);                                           \
    _Pragma("unroll")                                                        \
    for (int mi = 0; mi < 4; ++mi)                                           \
      _Pragma("unroll")                                                      \
      for (int ni = 0; ni < 4; ++ni)                                         \
        acc[mi][ni] = __builtin_amdgcn_mfma_f32_16x16x32_bf16(af_[mi], bq_[ni], acc[mi][ni], 0, 0, 0); \
    __builtin_amdgcn_s_setprio(0);                                           \
  } while (0)

#define SUBSTEP(T, SB, CB) do {                                              \
    asm volatile("s_waitcnt vmcnt(4)" ::: "memory");                         \
    __builtin_amdgcn_s_barrier();                                            \
    FENCE();                                                                 \
    STAGE4((T), (SB));                                                       \
    COMPUTE(CB);                                                             \
    FENCE();                                                                 \
  } while (0)

  // prologue: tiles 0,1 into bufs 0,1 (ring fills; no wait yet)
  STAGE4(0, 0);
  STAGE4(1, 1);

  for (int t = 0; t < 30; t += 3) {
    SUBSTEP(t + 2, 2, 0);
    SUBSTEP(t + 3, 0, 1);
    SUBSTEP(t + 4, 1, 2);
  }
  asm volatile("s_waitcnt vmcnt(4)" ::: "memory");
  __builtin_amdgcn_s_barrier();
  FENCE();
  COMPUTE(0);
  asm volatile("s_waitcnt vmcnt(0)" ::: "memory");
  __builtin_amdgcn_s_barrier();
  FENCE();
  COMPUTE(1);

#undef SUBSTEP
#undef COMPUTE
#undef STAGE4

#pragma unroll
  for (int mi = 0; mi < 4; ++mi) {
#pragma unroll
    for (int reg = 0; reg < 4; ++reg) {
      const int m = m0 + wr * 64 + mi * 16 + quad * 4 + reg;
#pragma unroll
      for (int ni = 0; ni < 4; ++ni) {
        const int e = n0 + wc * 64 + ni * 16 + l15;
        outF[(size_t)m * DM + e] = acc[mi][ni][reg];
      }
    }
  }
}

// ---------------------------------------------------------------------------
// MFMA flash attention on 32x32x16, swapped QK^T, in-register softmax+P.
// (R15-verified; see that round's header comment for the layout derivation.)
// ---------------------------------------------------------------------------
__global__ __launch_bounds__(256, 4) void attn_mfma(const unsigned short* __restrict__ Q,
                                                    const unsigned short* __restrict__ K,
                                                    const unsigned short* __restrict__ V,
                                                    unsigned short* __restrict__ O) {
  __shared__ unsigned short Ks[64][72];
  __shared__ unsigned short Vt[64][72];
  const int bh = blockIdx.x;                 // 0..63
  const int bx = 15 - (int)blockIdx.y;       // heavy q-blocks dispatched first
  const int tid = threadIdx.x;
  const int w = tid >> 6, lane = tid & 63;
  const int l31 = lane & 31, hi = lane >> 5;
  const size_t base = (size_t)bh * S_LEN * HD;
  const int b = bh >> 4, h = bh & 15;
  const int wq0 = bx * 128 + w * 32;
  const int diag_jt = 2 * bx + (w >> 1);     // wave's last (and partial) tile
  const int jt_blk = 2 * bx + 1;             // block's last tile
  const int kr0 = tid >> 3, kc0 = (tid & 7) * 8;
  const int vs = (tid & 31) * 2, vh = (tid >> 5) * 8;

  // Q fragments (B-operand): lane (hi,q=l31) holds d = ds*16 + hi*8 + e
  bf16x8 qb[4];
#pragma unroll
  for (int ds = 0; ds < 4; ++ds)
    qb[ds] = *(const bf16x8*)(Q + base + (size_t)(wq0 + l31) * HD + ds * 16 + hi * 8);

  f32x16 o0, o1;
#pragma unroll
  for (int r = 0; r < 16; ++r) { o0[r] = 0.f; o1[r] = 0.f; }
  float l_acc = 0.f;

  for (int jt = 0; jt <= jt_blk; ++jt) {
    __syncthreads();
    {
      const unsigned short* kgp = K + base + (size_t)jt * 64 * HD;
      const unsigned short* vgp = V + base + (size_t)jt * 64 * HD;
      *(uint4*)&Ks[kr0][kc0]      = *(const uint4*)(kgp + kr0 * HD + kc0);
      *(uint4*)&Ks[kr0 + 32][kc0] = *(const uint4*)(kgp + (kr0 + 32) * HD + kc0);
      uint4 r0 = *(const uint4*)(vgp + (size_t)vs * HD + vh);
      uint4 r1 = *(const uint4*)(vgp + (size_t)(vs + 1) * HD + vh);
      const unsigned int* a0 = (const unsigned int*)&r0;
      const unsigned int* a1 = (const unsigned int*)&r1;
#pragma unroll
      for (int j = 0; j < 4; ++j) {
        *(unsigned int*)&Vt[vh + 2 * j][vs]     = __builtin_amdgcn_perm(a1[j], a0[j], 0x05040100u);
        *(unsigned int*)&Vt[vh + 2 * j + 1][vs] = __builtin_amdgcn_perm(a1[j], a0[j], 0x07060302u);
      }
    }
    __syncthreads();

    if (jt <= diag_jt) {                      // wave-uniform
      const bool diag = (jt == diag_jt);
      for (int kb = 0; kb < 2; ++kb) {
        const bool kb_zero = diag && ((w & 1) == 0) && (kb == 1);
        const bool kb_part = diag && (kb == (w & 1));
        if (kb_zero) continue;                // wave-uniform; no contribution

        f32x16 sa;
#pragma unroll
        for (int r = 0; r < 16; ++r) sa[r] = 0.f;
        __builtin_amdgcn_s_setprio(1);
#pragma unroll
        for (int ds = 0; ds < 4; ++ds) {
          bf16x8 kf = *(const bf16x8*)&Ks[kb * 32 + l31][ds * 16 + hi * 8];
          sa = __builtin_amdgcn_mfma_f32_32x32x16_bf16(kf, qb[ds], sa, 0, 0, 0);
        }
        __builtin_amdgcn_s_setprio(0);

        float p[16];
        if (kb_part) {
#pragma unroll
          for (int r = 0; r < 16; ++r) {
            const int krel = (r & 3) + 8 * (r >> 2) + 4 * hi;
            p[r] = __expf((l31 >= krel) ? sa[r] : -1.0e30f);
          }
        } else {
#pragma unroll
          for (int r = 0; r < 16; ++r) p[r] = __expf(sa[r]);
        }
        l_acc += (((p[0] + p[1]) + (p[2] + p[3])) + ((p[4] + p[5]) + (p[6] + p[7])))
               + (((p[8] + p[9]) + (p[10] + p[11])) + ((p[12] + p[13]) + (p[14] + p[15])));

        unsigned int pk[8], sk[8];
#pragma unroll
        for (int g = 0; g < 4; ++g) {
          pk[2 * g]     = __builtin_amdgcn_perm(__float_as_uint(p[4 * g + 1]), __float_as_uint(p[4 * g]),     0x07060302u);
          pk[2 * g + 1] = __builtin_amdgcn_perm(__float_as_uint(p[4 * g + 3]), __float_as_uint(p[4 * g + 2]), 0x07060302u);
        }
#pragma unroll
        for (int i = 0; i < 8; ++i) sk[i] = (unsigned int)__shfl_xor((int)pk[i], 32);

#pragma unroll
        for (int sl = 0; sl < 2; ++sl) {
          const int g0 = 2 * sl, g1 = 2 * sl + 1;
          union { unsigned int u[4]; bf16x8 v; } fa;
          fa.u[0] = hi ? sk[2 * g1]     : pk[2 * g0];
          fa.u[1] = hi ? sk[2 * g1 + 1] : pk[2 * g0 + 1];
          fa.u[2] = hi ? pk[2 * g1]     : sk[2 * g0];
          fa.u[3] = hi ? pk[2 * g1 + 1] : sk[2 * g0 + 1];
          const int s = kb * 2 + sl;
          bf16x8 v0 = *(const bf16x8*)&Vt[l31][s * 16 + hi * 8];
          bf16x8 v1 = *(const bf16x8*)&Vt[32 + l31][s * 16 + hi * 8];
          __builtin_amdgcn_s_setprio(1);
          o0 = __builtin_amdgcn_mfma_f32_32x32x16_bf16(fa.v, v0, o0, 0, 0, 0);
          o1 = __builtin_amdgcn_mfma_f32_32x32x16_bf16(fa.v, v1, o1, 0, 0, 0);
          __builtin_amdgcn_s_setprio(0);
        }
      }
    }
  }

  // epilogue: l total (xor32 joins the two k-halves), scale + write O
  const float lf = l_acc + __shfl_xor(l_acc, 32);
  const float inv = 1.0f / lf;
#pragma unroll
  for (int r = 0; r < 16; ++r) {
    const int qrel = (r & 3) + 8 * (r >> 2) + 4 * hi;
    const float invr = __shfl(inv, qrel);    // lane qrel holds l for q=wq0+qrel
    const size_t orow = (size_t)(b * S_LEN + wq0 + qrel) * DM + h * HD;
    O[orow + l31]      = f2bf(o0[r] * invr);
    O[orow + 32 + l31] = f2bf(o1[r] * invr);
  }
}

extern "C" void kernel_launch(void* const* d_in, const int* in_sizes, int n_in,
                              void* d_out, int out_size, void* d_ws, size_t ws_size,
                              hipStream_t stream) {
  const float* x  = (const float*)d_in[0];  // fp32 [4,2048,1024]
  const float* wq = (const float*)d_in[1];  // fp32 [1024,1024]
  const float* wk = (const float*)d_in[2];
  const float* wv = (const float*)d_in[3];
  const float* wo = (const float*)d_in[4];

  unsigned short* Qb = (unsigned short*)d_ws;                 // 16 MB
  unsigned short* Kb = Qb + (size_t)M_ROWS * DM;              // 16 MB (Qb+z*16M)
  unsigned short* Vb = Kb + (size_t)M_ROWS * DM;              // 16 MB
  unsigned short* Xb = Vb + (size_t)M_ROWS * DM;              // 16 MB (alias Ob)
  unsigned short* Ob = Xb;
  (void)Kb; (void)Vb;

  // bf16 weight stash inside d_out (32 MB fp32 buffer; dead until final GEMM)
  unsigned short* Wstash = (unsigned short*)d_out;            // [3072][1024] bf16

  dim3 bb(256);
  dim3 gb(512);

  hipLaunchKernelGGL(cvt_bf16, dim3((M_ROWS * DM) / 2048), bb, 0, stream, x, Xb);
  hipLaunchKernelGGL(cvt_w3, dim3(3 * (DM * DM) / 2048), bb, 0, stream, wq, wk, wv, Wstash);
  // fused QKV as single GEMM: M=8192, N=3072 (z = e>>10 selects output slab)
  hipLaunchKernelGGL(gemm_qkv, dim3(M_ROWS / 256, 3 * DM / 128), gb, 0, stream,
                     Xb, Wstash, Qb);
  hipLaunchKernelGGL(attn_mfma, dim3(64, 16), bb, 0, stream, Qb, Qb + (size_t)M_ROWS * DM,
                     Qb + 2 * (size_t)M_ROWS * DM, Ob);
  // wo -> bf16 into Qb (free after attention); then final projection
  hipLaunchKernelGGL(cvt_bf16, dim3((DM * DM) / 2048), bb, 0, stream, wo, Qb);
  hipLaunchKernelGGL(gemm_out, dim3(M_ROWS / 128, DM / 128), bb, 0, stream,
                     Ob, Qb, (float*)d_out);
}

// Round 13
// 194.365 us; speedup vs baseline: 1.3277x; 1.0252x over previous
//
#include <hip/hip_runtime.h>
#include <hip/hip_bf16.h>
#include <math.h>

// Problem: MultiHeadSelfAttention  B=4, S=2048, D=1024, H=16, Hd=64
// fp32 in / fp32 out. bf16 scratch, fp32 accumulation.
// Round 22:
//  - attn: T14 async-stage + LDS double-buffer. Was: per-jt {bar; load;
//    LDS-write; bar; compute} -> load latency exposed inside barrier pair.
//    Now: ONE barrier/jt; issue jt+1 global->regs; compute jt from
//    buf[jt&1]; write regs->buf[(jt+1)&1]. Hazard proof: buf[cb^1] last
//    read in iteration jt-1 (completes before this iteration's barrier);
//    write after barrier; readers see it after next barrier. LDS 36.9KB
//    (4 blocks/CU = 147KB ok), VGPR +16 prefetch (<128 cap).
//  - QKV gemm: R16 exact, frozen (structure ledger closed: 2ph geometries,
//    8ph port, A-direct all falsified; 93.5us verified 3x).
//  - final gemm: R18-128^2/4w, frozen (R21-verified).
// ws: Qb@0, Kb@16M, Vb@32M, Xb/Ob@48M (aliased). Wstash in d_out (dead
// until final GEMM); wo converted into Qb after attention frees it.

#define S_LEN 2048
#define DM    1024
#define NH    16
#define HD    64
#define M_ROWS 8192   // B * S

typedef __attribute__((ext_vector_type(8))) short bf16x8;
typedef __attribute__((ext_vector_type(4))) float f32x4;
typedef __attribute__((ext_vector_type(16))) float f32x16;

__device__ __forceinline__ float bf2f(unsigned short u) {
  union { unsigned int i; float f; } c; c.i = ((unsigned int)u) << 16; return c.f;
}
__device__ __forceinline__ unsigned short f2bf(float f) {
  unsigned int x = __float_as_uint(f);
  if ((x & 0x7fffffffu) > 0x7f800000u) return (unsigned short)0x7fc0u;  // NaN
  return (unsigned short)((x + 0x7fffu + ((x >> 16) & 1u)) >> 16);      // RNE
}
// async global->LDS, 16 B per lane; lds dest must be wave-uniform
__device__ __forceinline__ void gl_lds16(const unsigned short* g, unsigned short* l) {
  __builtin_amdgcn_global_load_lds(
      (const __attribute__((address_space(1))) unsigned int*)g,
      (__attribute__((address_space(3))) unsigned int*)l, 16, 0, 0);
}

#define FENCE() asm volatile("" ::: "memory")

// ---------------------------------------------------------------------------
// fp32 -> bf16 bulk convert (8 elems/thread)
// ---------------------------------------------------------------------------
__global__ __launch_bounds__(256) void cvt_bf16(const float* __restrict__ in,
                                                unsigned short* __restrict__ out) {
  const int i = blockIdx.x * 256 + threadIdx.x;
  float4 a = ((const float4*)in)[2 * i];
  float4 b = ((const float4*)in)[2 * i + 1];
  ushort4 r0, r1;
  r0.x = f2bf(a.x); r0.y = f2bf(a.y); r0.z = f2bf(a.z); r0.w = f2bf(a.w);
  r1.x = f2bf(b.x); r1.y = f2bf(b.y); r1.z = f2bf(b.z); r1.w = f2bf(b.w);
  ((ushort4*)out)[2 * i] = r0;
  ((ushort4*)out)[2 * i + 1] = r1;
}

// convert wq,wk,wv (1M fp32 each) into one contiguous bf16 stash [3072][1024]
__global__ __launch_bounds__(256) void cvt_w3(const float* __restrict__ w0,
                                              const float* __restrict__ w1,
                                              const float* __restrict__ w2,
                                              unsigned short* __restrict__ out) {
  const int idx = blockIdx.x;                 // 0..1535
  const int which = idx >> 9;
  const float* src = (which == 0) ? w0 : (which == 1) ? w1 : w2;
  unsigned short* dst = out + (size_t)which * (DM * DM);
  const int i = (idx & 511) * 256 + threadIdx.x;
  float4 a = ((const float4*)src)[2 * i];
  float4 b = ((const float4*)src)[2 * i + 1];
  ushort4 r0, r1;
  r0.x = f2bf(a.x); r0.y = f2bf(a.y); r0.z = f2bf(a.z); r0.w = f2bf(a.w);
  r1.x = f2bf(b.x); r1.y = f2bf(b.y); r1.z = f2bf(b.z); r1.w = f2bf(b.w);
  ((ushort4*)dst)[2 * i] = r0;
  ((ushort4*)dst)[2 * i + 1] = r1;
}

// ---------------------------------------------------------------------------
// QKV GEMM (R16 exact): counted-vmcnt ring-3, 256x128, 8 waves, 1 bar/K-step.
// C[m,e] = sum_d A[m,d] * Wall[e,d].  bf16 out, z-slab scatter.
// ---------------------------------------------------------------------------
__global__ __launch_bounds__(512, 4) void gemm_qkv(const unsigned short* __restrict__ A,
                                                   const unsigned short* __restrict__ Wall,
                                                   unsigned short* __restrict__ outB) {
  __shared__ __align__(16) unsigned short As[3 * 8192];  // [buf][kgrp4][256][8]
  __shared__ __align__(16) unsigned short Bs[3 * 4096];  // [buf][kgrp4][128][8]
  const int m0 = blockIdx.x * 256;
  const int n0 = blockIdx.y * 128;
  const int tid = threadIdx.x;
  const int lane = tid & 63, w = tid >> 6;
  const int quad = lane >> 4, l15 = lane & 15;
  const int wrow = w >> 1, wcol = w & 1;    // compute mapping: 4M x 2N waves

  const int skg = w & 3, srq = w >> 2;
  const unsigned short* agA = A    + (size_t)(m0 + srq * 64 + lane) * DM + skg * 8;
  const unsigned short* bgB = Wall + (size_t)(n0 + srq * 64 + lane) * DM + skg * 8;
  const int lA0 = skg * 2048 + srq * 512;   // wave-uniform LDS elem offsets
  const int lA1 = lA0 + 1024;               // rows +128
  const int lB  = skg * 1024 + srq * 512;
  const int raA = quad * 2048 + (wrow * 64 + l15) * 8;  // frag-read bases
  const int raB = quad * 1024 + (wcol * 64 + l15) * 8;

  f32x4 acc[4][4];
#pragma unroll
  for (int i = 0; i < 4; ++i)
#pragma unroll
    for (int j = 0; j < 4; ++j) { acc[i][j].x = 0.f; acc[i][j].y = 0.f; acc[i][j].z = 0.f; acc[i][j].w = 0.f; }

#define STAGE3(T, SB) do {                                                   \
    const unsigned short* ap_ = agA + (size_t)(T) * 32;                      \
    gl_lds16(ap_,          &As[(SB) * 8192 + lA0]);                          \
    gl_lds16(ap_ + 131072, &As[(SB) * 8192 + lA1]);                          \
    gl_lds16(bgB + (size_t)(T) * 32, &Bs[(SB) * 4096 + lB]);                 \
  } while (0)

#define COMPUTE(CB) do {                                                     \
    bf16x8 af_[4], bq_[4];                                                   \
    _Pragma("unroll")                                                        \
    for (int mi = 0; mi < 4; ++mi)                                           \
      af_[mi] = *(const bf16x8*)&As[(CB) * 8192 + raA + mi * 128];           \
    _Pragma("unroll")                                                        \
    for (int ni = 0; ni < 4; ++ni)                                           \
      bq_[ni] = *(const bf16x8*)&Bs[(CB) * 4096 + raB + ni * 128];           \
    __builtin_amdgcn_s_setprio(1);                                           \
    _Pragma("unroll")                                                        \
    for (int mi = 0; mi < 4; ++mi)                                           \
      _Pragma("unroll")                                                      \
      for (int ni = 0; ni < 4; ++ni)                                         \
        acc[mi][ni] = __builtin_amdgcn_mfma_f32_16x16x32_bf16(af_[mi], bq_[ni], acc[mi][ni], 0, 0, 0); \
    __builtin_amdgcn_s_setprio(0);                                           \
  } while (0)

#define SUBSTEP(T, SB, CB) do {                                              \
    asm volatile("s_waitcnt vmcnt(3)" ::: "memory");                         \
    __builtin_amdgcn_s_barrier();                                            \
    FENCE();                                                                 \
    STAGE3((T), (SB));                                                       \
    COMPUTE(CB);                                                             \
    FENCE();                                                                 \
  } while (0)

  STAGE3(0, 0);
  STAGE3(1, 1);

  for (int t = 0; t < 30; t += 3) {
    SUBSTEP(t + 2, 2, 0);
    SUBSTEP(t + 3, 0, 1);
    SUBSTEP(t + 4, 1, 2);
  }
  asm volatile("s_waitcnt vmcnt(3)" ::: "memory");
  __builtin_amdgcn_s_barrier();
  FENCE();
  COMPUTE(0);
  asm volatile("s_waitcnt vmcnt(0)" ::: "memory");
  __builtin_amdgcn_s_barrier();
  FENCE();
  COMPUTE(1);

#undef SUBSTEP
#undef COMPUTE
#undef STAGE3

  const float oscale = (n0 < 1024) ? 0.125f : 1.0f;
#pragma unroll
  for (int mi = 0; mi < 4; ++mi) {
#pragma unroll
    for (int reg = 0; reg < 4; ++reg) {
      const int m = m0 + wrow * 64 + mi * 16 + quad * 4 + reg;
#pragma unroll
      for (int ni = 0; ni < 4; ++ni) {
        const int e = n0 + wcol * 64 + ni * 16 + l15;
        const float v = acc[mi][ni][reg];
        const int z = e >> 10;                   // 0:Q 1:K 2:V
        const int e10 = e & 1023;
        const int b = m >> 11, s = m & (S_LEN - 1);
        const int h = e10 >> 6, hd = e10 & 63;
        outB[(size_t)z * (M_ROWS * DM) +
             (((size_t)(b * NH + h)) * S_LEN + s) * HD + hd] = f2bf(v * oscale);
      }
    }
  }
}

// ---------------------------------------------------------------------------
// Final GEMM (R18-verified 128^2/4w): counted-vmcnt ring-3, fp32 out.
// ---------------------------------------------------------------------------
__global__ __launch_bounds__(256, 2) void gemm_out(const unsigned short* __restrict__ A,
                                                   const unsigned short* __restrict__ Wb,
                                                   float* __restrict__ outF) {
  __shared__ __align__(16) unsigned short As[3 * 4096];  // [buf][kgrp4][128][8]
  __shared__ __align__(16) unsigned short Bs[3 * 4096];
  const int m0 = blockIdx.x * 128;
  const int n0 = blockIdx.y * 128;
  const int tid = threadIdx.x;
  const int lane = tid & 63, w = tid >> 6;   // 4 waves
  const int quad = lane >> 4, l15 = lane & 15;
  const int wr = w >> 1, wc = w & 1;         // compute mapping: 2M x 2N waves

  const unsigned short* agA = A  + (size_t)(m0 + lane) * DM + w * 8;
  const unsigned short* bgB = Wb + (size_t)(n0 + lane) * DM + w * 8;
  const int lA0 = w * 1024;                  // elem base (kgrp=w, rows 0..63)
  const int lB0 = w * 1024;
  const int raA = quad * 1024 + (wr * 64 + l15) * 8;  // frag-read bases
  const int raB = quad * 1024 + (wc * 64 + l15) * 8;

  f32x4 acc[4][4];
#pragma unroll
  for (int i = 0; i < 4; ++i)
#pragma unroll
    for (int j = 0; j < 4; ++j) { acc[i][j].x = 0.f; acc[i][j].y = 0.f; acc[i][j].z = 0.f; acc[i][j].w = 0.f; }

#define STAGE4(T, SB) do {                                                   \
    const unsigned short* ap_ = agA + (size_t)(T) * 32;                      \
    const unsigned short* bp_ = bgB + (size_t)(T) * 32;                      \
    gl_lds16(ap_,           &As[(SB) * 4096 + lA0]);                         \
    gl_lds16(ap_ + 64 * DM, &As[(SB) * 4096 + lA0 + 512]);                   \
    gl_lds16(bp_,           &Bs[(SB) * 4096 + lB0]);                         \
    gl_lds16(bp_ + 64 * DM, &Bs[(SB) * 4096 + lB0 + 512]);                   \
  } while (0)

#define COMPUTE(CB) do {                                                     \
    bf16x8 af_[4], bq_[4];                                                   \
    _Pragma("unroll")                                                        \
    for (int mi = 0; mi < 4; ++mi)                                           \
      af_[mi] = *(const bf16x8*)&As[(CB) * 4096 + raA + mi * 128];           \
    _Pragma("unroll")                                                        \
    for (int ni = 0; ni < 4; ++ni)                                           \
      bq_[ni] = *(const bf16x8*)&Bs[(CB) * 4096 + raB + ni * 128];           \
    __builtin_amdgcn_s_setprio(1);                                           \
    _Pragma("unroll")                                                        \
    for (int mi = 0; mi < 4; ++mi)                                           \
      _Pragma("unroll")                                                      \
      for (int ni = 0; ni < 4; ++ni)                                         \
        acc[mi][ni] = __builtin_amdgcn_mfma_f32_16x16x32_bf16(af_[mi], bq_[ni], acc[mi][ni], 0, 0, 0); \
    __builtin_amdgcn_s_setprio(0);                                           \
  } while (0)

#define SUBSTEP(T, SB, CB) do {                                              \
    asm volatile("s_waitcnt vmcnt(4)" ::: "memory");                         \
    __builtin_amdgcn_s_barrier();                                            \
    FENCE();                                                                 \
    STAGE4((T), (SB));                                                       \
    COMPUTE(CB);                                                             \
    FENCE();                                                                 \
  } while (0)

  STAGE4(0, 0);
  STAGE4(1, 1);

  for (int t = 0; t < 30; t += 3) {
    SUBSTEP(t + 2, 2, 0);
    SUBSTEP(t + 3, 0, 1);
    SUBSTEP(t + 4, 1, 2);
  }
  asm volatile("s_waitcnt vmcnt(4)" ::: "memory");
  __builtin_amdgcn_s_barrier();
  FENCE();
  COMPUTE(0);
  asm volatile("s_waitcnt vmcnt(0)" ::: "memory");
  __builtin_amdgcn_s_barrier();
  FENCE();
  COMPUTE(1);

#undef SUBSTEP
#undef COMPUTE
#undef STAGE4

#pragma unroll
  for (int mi = 0; mi < 4; ++mi) {
#pragma unroll
    for (int reg = 0; reg < 4; ++reg) {
      const int m = m0 + wr * 64 + mi * 16 + quad * 4 + reg;
#pragma unroll
      for (int ni = 0; ni < 4; ++ni) {
        const int e = n0 + wc * 64 + ni * 16 + l15;
        outF[(size_t)m * DM + e] = acc[mi][ni][reg];
      }
    }
  }
}

// ---------------------------------------------------------------------------
// MFMA flash attention on 32x32x16, swapped QK^T, in-register softmax+P.
// R22: LDS double-buffered K/V + T14 async-stage. Per jt: ONE barrier;
// issue jt+1 global->regs; compute jt from buf[jt&1]; write regs ->
// buf[(jt+1)&1]. (Compute math byte-identical to R15-verified.)
// ---------------------------------------------------------------------------
__global__ __launch_bounds__(256, 4) void attn_mfma(const unsigned short* __restrict__ Q,
                                                    const unsigned short* __restrict__ K,
                                                    const unsigned short* __restrict__ V,
                                                    unsigned short* __restrict__ O) {
  __shared__ unsigned short Ks[2][64][72];
  __shared__ unsigned short Vt[2][64][72];
  const int bh = blockIdx.x;                 // 0..63
  const int bx = 15 - (int)blockIdx.y;       // heavy q-blocks dispatched first
  const int tid = threadIdx.x;
  const int w = tid >> 6, lane = tid & 63;
  const int l31 = lane & 31, hi = lane >> 5;
  const size_t base = (size_t)bh * S_LEN * HD;
  const int b = bh >> 4, h = bh & 15;
  const int wq0 = bx * 128 + w * 32;
  const int diag_jt = 2 * bx + (w >> 1);     // wave's last (and partial) tile
  const int jt_blk = 2 * bx + 1;             // block's last tile
  const int kr0 = tid >> 3, kc0 = (tid & 7) * 8;
  const int vs = (tid & 31) * 2, vh = (tid >> 5) * 8;

  // Q fragments (B-operand): lane (hi,q=l31) holds d = ds*16 + hi*8 + e
  bf16x8 qb[4];
#pragma unroll
  for (int ds = 0; ds < 4; ++ds)
    qb[ds] = *(const bf16x8*)(Q + base + (size_t)(wq0 + l31) * HD + ds * 16 + hi * 8);

  f32x16 o0, o1;
#pragma unroll
  for (int r = 0; r < 16; ++r) { o0[r] = 0.f; o1[r] = 0.f; }
  float l_acc = 0.f;

  // prologue: tile 0 -> regs -> buf 0 (no barrier needed before first use;
  // the loop-top barrier covers visibility)
  uint4 kA, kB, vA, vB;
  {
    const unsigned short* kgp = K + base;
    const unsigned short* vgp = V + base;
    kA = *(const uint4*)(kgp + kr0 * HD + kc0);
    kB = *(const uint4*)(kgp + (kr0 + 32) * HD + kc0);
    vA = *(const uint4*)(vgp + (size_t)vs * HD + vh);
    vB = *(const uint4*)(vgp + (size_t)(vs + 1) * HD + vh);
  }
  {
    *(uint4*)&Ks[0][kr0][kc0]      = kA;
    *(uint4*)&Ks[0][kr0 + 32][kc0] = kB;
    const unsigned int* a0 = (const unsigned int*)&vA;
    const unsigned int* a1 = (const unsigned int*)&vB;
#pragma unroll
    for (int j = 0; j < 4; ++j) {
      *(unsigned int*)&Vt[0][vh + 2 * j][vs]     = __builtin_amdgcn_perm(a1[j], a0[j], 0x05040100u);
      *(unsigned int*)&Vt[0][vh + 2 * j + 1][vs] = __builtin_amdgcn_perm(a1[j], a0[j], 0x07060302u);
    }
  }

  for (int jt = 0; jt <= jt_blk; ++jt) {
    const int cb = jt & 1;
    __syncthreads();   // buf[cb] writes visible; all reads of buf[cb^1] done

    // T14: issue next tile's global loads now; consumed by the LDS write
    // AFTER compute -> latency hides under QK/softmax/PV
    if (jt < jt_blk) {
      const unsigned short* kgp = K + base + (size_t)(jt + 1) * 64 * HD;
      const unsigned short* vgp = V + base + (size_t)(jt + 1) * 64 * HD;
      kA = *(const uint4*)(kgp + kr0 * HD + kc0);
      kB = *(const uint4*)(kgp + (kr0 + 32) * HD + kc0);
      vA = *(const uint4*)(vgp + (size_t)vs * HD + vh);
      vB = *(const uint4*)(vgp + (size_t)(vs + 1) * HD + vh);
    }

    if (jt <= diag_jt) {                      // wave-uniform
      const bool diag = (jt == diag_jt);
      for (int kb = 0; kb < 2; ++kb) {
        const bool kb_zero = diag && ((w & 1) == 0) && (kb == 1);
        const bool kb_part = diag && (kb == (w & 1));
        if (kb_zero) continue;                // wave-uniform; no contribution

        f32x16 sa;
#pragma unroll
        for (int r = 0; r < 16; ++r) sa[r] = 0.f;
        __builtin_amdgcn_s_setprio(1);
#pragma unroll
        for (int ds = 0; ds < 4; ++ds) {
          bf16x8 kf = *(const bf16x8*)&Ks[cb][kb * 32 + l31][ds * 16 + hi * 8];
          sa = __builtin_amdgcn_mfma_f32_32x32x16_bf16(kf, qb[ds], sa, 0, 0, 0);
        }
        __builtin_amdgcn_s_setprio(0);

        float p[16];
        if (kb_part) {
#pragma unroll
          for (int r = 0; r < 16; ++r) {
            const int krel = (r & 3) + 8 * (r >> 2) + 4 * hi;
            p[r] = __expf((l31 >= krel) ? sa[r] : -1.0e30f);
          }
        } else {
#pragma unroll
          for (int r = 0; r < 16; ++r) p[r] = __expf(sa[r]);
        }
        l_acc += (((p[0] + p[1]) + (p[2] + p[3])) + ((p[4] + p[5]) + (p[6] + p[7])))
               + (((p[8] + p[9]) + (p[10] + p[11])) + ((p[12] + p[13]) + (p[14] + p[15])));

        unsigned int pk[8], sk[8];
#pragma unroll
        for (int g = 0; g < 4; ++g) {
          pk[2 * g]     = __builtin_amdgcn_perm(__float_as_uint(p[4 * g + 1]), __float_as_uint(p[4 * g]),     0x07060302u);
          pk[2 * g + 1] = __builtin_amdgcn_perm(__float_as_uint(p[4 * g + 3]), __float_as_uint(p[4 * g + 2]), 0x07060302u);
        }
#pragma unroll
        for (int i = 0; i < 8; ++i) sk[i] = (unsigned int)__shfl_xor((int)pk[i], 32);

#pragma unroll
        for (int sl = 0; sl < 2; ++sl) {
          const int g0 = 2 * sl, g1 = 2 * sl + 1;
          union { unsigned int u[4]; bf16x8 v; } fa;
          fa.u[0] = hi ? sk[2 * g1]     : pk[2 * g0];
          fa.u[1] = hi ? sk[2 * g1 + 1] : pk[2 * g0 + 1];
          fa.u[2] = hi ? pk[2 * g1]     : sk[2 * g0];
          fa.u[3] = hi ? pk[2 * g1 + 1] : sk[2 * g0 + 1];
          const int s = kb * 2 + sl;
          bf16x8 v0 = *(const bf16x8*)&Vt[cb][l31][s * 16 + hi * 8];
          bf16x8 v1 = *(const bf16x8*)&Vt[cb][32 + l31][s * 16 + hi * 8];
          __builtin_amdgcn_s_setprio(1);
          o0 = __builtin_amdgcn_mfma_f32_32x32x16_bf16(fa.v, v0, o0, 0, 0, 0);
          o1 = __builtin_amdgcn_mfma_f32_32x32x16_bf16(fa.v, v1, o1, 0, 0, 0);
          __builtin_amdgcn_s_setprio(0);
        }
      }
    }

    // write tile jt+1 into the other buffer (safe: its last readers were
    // iteration jt-1, which completed before this iteration's barrier)
    if (jt < jt_blk) {
      const int nb = cb ^ 1;
      *(uint4*)&Ks[nb][kr0][kc0]      = kA;
      *(uint4*)&Ks[nb][kr0 + 32][kc0] = kB;
      const unsigned int* a0 = (const unsigned int*)&vA;
      const unsigned int* a1 = (const unsigned int*)&vB;
#pragma unroll
      for (int j = 0; j < 4; ++j) {
        *(unsigned int*)&Vt[nb][vh + 2 * j][vs]     = __builtin_amdgcn_perm(a1[j], a0[j], 0x05040100u);
        *(unsigned int*)&Vt[nb][vh + 2 * j + 1][vs] = __builtin_amdgcn_perm(a1[j], a0[j], 0x07060302u);
      }
    }
  }

  // epilogue: l total (xor32 joins the two k-halves), scale + write O
  const float lf = l_acc + __shfl_xor(l_acc, 32);
  const float inv = 1.0f / lf;
#pragma unroll
  for (int r = 0; r < 16; ++r) {
    const int qrel = (r & 3) + 8 * (r >> 2) + 4 * hi;
    const float invr = __shfl(inv, qrel);    // lane qrel holds l for q=wq0+qrel
    const size_t orow = (size_t)(b * S_LEN + wq0 + qrel) * DM + h * HD;
    O[orow + l31]      = f2bf(o0[r] * invr);
    O[orow + 32 + l31] = f2bf(o1[r] * invr);
  }
}

extern "C" void kernel_launch(void* const* d_in, const int* in_sizes, int n_in,
                              void* d_out, int out_size, void* d_ws, size_t ws_size,
                              hipStream_t stream) {
  const float* x  = (const float*)d_in[0];  // fp32 [4,2048,1024]
  const float* wq = (const float*)d_in[1];  // fp32 [1024,1024]
  const float* wk = (const float*)d_in[2];
  const float* wv = (const float*)d_in[3];
  const float* wo = (const float*)d_in[4];

  unsigned short* Qb = (unsigned short*)d_ws;                 // 16 MB
  unsigned short* Kb = Qb + (size_t)M_ROWS * DM;              // 16 MB (Qb+z*16M)
  unsigned short* Vb = Kb + (size_t)M_ROWS * DM;              // 16 MB
  unsigned short* Xb = Vb + (size_t)M_ROWS * DM;              // 16 MB (alias Ob)
  unsigned short* Ob = Xb;
  (void)Kb; (void)Vb;

  // bf16 weight stash inside d_out (32 MB fp32 buffer; dead until final GEMM)
  unsigned short* Wstash = (unsigned short*)d_out;            // [3072][1024] bf16

  dim3 bb(256);
  dim3 gb(512);

  hipLaunchKernelGGL(cvt_bf16, dim3((M_ROWS * DM) / 2048), bb, 0, stream, x, Xb);
  hipLaunchKernelGGL(cvt_w3, dim3(3 * (DM * DM) / 2048), bb, 0, stream, wq, wk, wv, Wstash);
  // fused QKV as single GEMM: M=8192, N=3072 (z = e>>10 selects output slab)
  hipLaunchKernelGGL(gemm_qkv, dim3(M_ROWS / 256, 3 * DM / 128), gb, 0, stream,
                     Xb, Wstash, Qb);
  hipLaunchKernelGGL(attn_mfma, dim3(64, 16), bb, 0, stream, Qb, Qb + (size_t)M_ROWS * DM,
                     Qb + 2 * (size_t)M_ROWS * DM, Ob);
  // wo -> bf16 into Qb (free after attention); then final projection
  hipLaunchKernelGGL(cvt_bf16, dim3((DM * DM) / 2048), bb, 0, stream, wo, Qb);
  hipLaunchKernelGGL(gemm_out, dim3(M_ROWS / 128, DM / 128), bb, 0, stream,
                     Ob, Qb, (float*)d_out);
}